// Round 1
// baseline (3291.228 us; speedup 1.0000x reference)
//
#include <hip/hip_runtime.h>
#include <stdint.h>

typedef unsigned long long u64;
typedef unsigned int u32;

#define BB 8
#define NN 4096
#define SS 1024
#define EE 102      // int(0.1 * 1024)
#define NBB 3072    // N - S
#define FPS_T 512
#define SEL_T 512

// ---------------- FPS kernel: one block per batch ----------------
// Replicates _fps_order exactly: idxs[0]=0; iter: d = ||p - last||^2 (no FMA,
// (dx2+dy2)+dz2 order), mind = min(mind, d), next = argmax(mind) with
// lowest-index tie break (np/jnp argmax = first max).
__global__ __launch_bounds__(FPS_T) void fps_kernel(const float* __restrict__ x,
                                                    int* __restrict__ idxs) {
  const int b = blockIdx.x;
  const int t = threadIdx.x;
  const float* xb = x + (size_t)b * NN * 3;

  __shared__ float lx[NN], ly[NN], lz[NN];   // 48 KB coord mirror for broadcast
  __shared__ u64 red[3];                     // 3-slot rotation, 1 barrier/iter

  float px[8], py[8], pz[8], mind[8];
#pragma unroll
  for (int q = 0; q < 8; ++q) {
    int i = q * FPS_T + t;
    float a = xb[i * 3 + 0];
    float c = xb[i * 3 + 1];
    float d = xb[i * 3 + 2];
    px[q] = a; py[q] = c; pz[q] = d;
    lx[i] = a; ly[i] = c; lz[i] = d;
    mind[q] = __builtin_inff();
  }
  if (t < 3) red[t] = 0ULL;
  if (t == 0) idxs[(size_t)b * NN] = 0;
  __syncthreads();

  int last = 0;
  for (int it = 0; it < NN - 1; ++it) {
    float lpx = lx[last], lpy = ly[last], lpz = lz[last];
    float bestv = -1.0f;
    int besti = 0;
#pragma unroll
    for (int q = 0; q < 8; ++q) {
      // exact, non-contracted arithmetic to match XLA CPU elementwise+reduce
      float dx = __fsub_rn(px[q], lpx);
      float dy = __fsub_rn(py[q], lpy);
      float dz = __fsub_rn(pz[q], lpz);
      float dd = __fadd_rn(__fadd_rn(__fmul_rn(dx, dx), __fmul_rn(dy, dy)),
                           __fmul_rn(dz, dz));
      float m = fminf(mind[q], dd);
      mind[q] = m;
      // ascending q => ascending global index; strict '>' keeps lowest index
      if (m > bestv) { bestv = m; besti = q * FPS_T + t; }
    }
    // pack (value desc, index asc) into one u64: higher key wins
    u64 key = ((u64)__float_as_uint(bestv) << 32) |
              (u64)(0xFFFFFFFFu - (u32)besti);
#pragma unroll
    for (int s = 1; s < 64; s <<= 1) {
      u64 o = __shfl_xor(key, s, 64);
      if (o > key) key = o;
    }
    int slot = it % 3;
    if ((t & 63) == 0) atomicMax(&red[slot], key);
    // reset the slot for iteration it+1; its last readers finished before
    // barrier(it-1), which every wave here has already passed.
    if (t == 0) red[(slot + 1) % 3] = 0ULL;
    __syncthreads();
    u64 w = red[slot];
    last = (int)(0xFFFFFFFFu - (u32)(w & 0xFFFFFFFFu));
    if (t == 0) idxs[(size_t)b * NN + it + 1] = last;
  }
}

// ------------- selection kernel: one block per batch -------------
// curvn = (curv - min) / (max - min)   [max(curv-min) == fl(max-min): rounding
// is monotone], sc[i] = (1 - idxs[i]/4095) * curvn[i]  (jnp.linspace exact,
// endpoint exact 0). Then stable sorts via u64 keys + the collapsed
// final[] formula, and output writes (final as float, sampled floats).
__global__ __launch_bounds__(SEL_T) void select_kernel(const float* __restrict__ x,
                                                       const float* __restrict__ curv,
                                                       const int* __restrict__ idxs,
                                                       float* __restrict__ out) {
  const int b = blockIdx.x;
  const int t = threadIdx.x;
  __shared__ u64 ka[SS];     // sca keys: (~vbits, i)  -> ascending == desc by v
  __shared__ u64 kb[4096];   // scb keys: (vbits, i)   -> ascending, 1024 pads
  __shared__ float rmn[8], rmx[8];

  const float* cb = curv + (size_t)b * NN;
  const int* ib = idxs + (size_t)b * NN;

  float mn = __builtin_inff(), mx = -__builtin_inff();
  float cv[8];
#pragma unroll
  for (int q = 0; q < 8; ++q) {
    float v = cb[q * SEL_T + t];
    cv[q] = v;
    mn = fminf(mn, v);
    mx = fmaxf(mx, v);
  }
#pragma unroll
  for (int s = 1; s < 64; s <<= 1) {
    mn = fminf(mn, __shfl_xor(mn, s, 64));
    mx = fmaxf(mx, __shfl_xor(mx, s, 64));
  }
  if ((t & 63) == 0) { rmn[t >> 6] = mn; rmx[t >> 6] = mx; }
  __syncthreads();
  mn = rmn[0]; mx = rmx[0];
#pragma unroll
  for (int w = 1; w < 8; ++w) { mn = fminf(mn, rmn[w]); mx = fmaxf(mx, rmx[w]); }
  float denom = __fsub_rn(mx, mn);

#pragma unroll
  for (int q = 0; q < 8; ++q) {
    int i = q * SEL_T + t;
    float cn = __fdiv_rn(__fsub_rn(cv[q], mn), denom);
    int id = ib[i];
    // jnp.linspace(1,0,4096)[id] = 1 - id/4095 (true division; id=4095 -> 0)
    float sv = __fsub_rn(1.0f, __fdiv_rn((float)id, 4095.0f));
    float scv = __fmul_rn(sv, cn);   // sc >= 0 always -> bits are order-monotone
    u32 vb = __float_as_uint(scv);
    if (i < SS)
      ka[i] = ((u64)(vb ^ 0xFFFFFFFFu) << 32) | (u32)i;
    else
      kb[i - SS] = ((u64)vb << 32) | (u32)(i - SS);
  }
  for (int i = NBB + t; i < 4096; i += SEL_T) kb[i] = ~0ULL;  // pads to the top
  __syncthreads();

  // bitonic sort ka ascending (n=1024, 512 pairs: one per thread)
  for (u32 k = 2; k <= SS; k <<= 1) {
    for (u32 j = k >> 1; j > 0; j >>= 1) {
      u32 p = (u32)t;
      u32 i = ((p & ~(j - 1)) << 1) | (p & (j - 1));
      u32 l = i | j;
      bool up = ((i & k) == 0);
      u64 a = ka[i], c = ka[l];
      if ((a > c) == up) { ka[i] = c; ka[l] = a; }
      __syncthreads();
    }
  }
  // bitonic sort kb ascending (n=4096, 2048 pairs: 4 per thread)
  for (u32 k = 2; k <= 4096; k <<= 1) {
    for (u32 j = k >> 1; j > 0; j >>= 1) {
#pragma unroll
      for (u32 p = (u32)t; p < 2048; p += SEL_T) {
        u32 i = ((p & ~(j - 1)) << 1) | (p & (j - 1));
        u32 l = i | j;
        bool up = ((i & k) == 0);
        u64 a = kb[i], c = kb[l];
        if ((a > c) == up) { kb[i] = c; kb[l] = a; }
      }
      __syncthreads();
    }
  }

  // final[j]: j<922 -> ba_idx[j]; else tb beats ba ? tb_idx[j] : ba_idx[j]
#pragma unroll
  for (int j0 = 0; j0 < SS; j0 += SEL_T) {
    int j = j0 + t;
    u64 A = ka[j];
    int baid = (int)(u32)(A & 0xFFFFFFFFu);
    u32 babits = ((u32)(A >> 32)) ^ 0xFFFFFFFFu;
    int fin = baid;
    if (j >= SS - EE) {
      u64 Bk = kb[2048 + j];           // largest-1024 of scb, ascending
      u32 tbbits = (u32)(Bk >> 32);
      if (tbbits > babits) fin = (int)(u32)(Bk & 0xFFFFFFFFu) + SS;
    }
    int pt = ib[fin];
    out[(size_t)b * SS + j] = (float)fin;
    const float* xp = x + ((size_t)b * NN + (size_t)pt) * 3;
    float* op = out + (size_t)BB * SS + ((size_t)b * SS + (size_t)j) * 3;
    op[0] = xp[0];
    op[1] = xp[1];
    op[2] = xp[2];
  }
}

extern "C" void kernel_launch(void* const* d_in, const int* in_sizes, int n_in,
                              void* d_out, int out_size, void* d_ws, size_t ws_size,
                              hipStream_t stream) {
  (void)in_sizes; (void)n_in; (void)out_size; (void)ws_size;
  const float* x = (const float*)d_in[0];
  const float* curv = (const float*)d_in[1];
  int* idxs = (int*)d_ws;             // B*N int32 = 128 KB scratch
  float* out = (float*)d_out;

  fps_kernel<<<BB, FPS_T, 0, stream>>>(x, idxs);
  select_kernel<<<BB, SEL_T, 0, stream>>>(x, curv, idxs, out);
}

// Round 2
// 2267.759 us; speedup vs baseline: 1.4513x; 1.4513x over previous
//
#include <hip/hip_runtime.h>
#include <stdint.h>

typedef unsigned long long u64;
typedef unsigned int u32;

#define BB 8
#define NN 4096
#define SS 1024
#define EE 102      // int(0.1 * 1024)
#define NBB 3072    // N - S
#define FT 256      // fps threads (4 waves)
#define PT 16       // points per thread (contiguous: thread t owns [16t,16t+16))
#define SEL_T 512

// DPP-based wave64 max-reduce step: fmax with lane (this - offset) via row ops.
// bound_ctrl=true: invalid source lanes read 0; all values >= 0 so identity.
template <int CTRL>
__device__ __forceinline__ float maxdpp(float v) {
  int m = __builtin_amdgcn_update_dpp(0, __float_as_int(v), CTRL, 0xf, 0xf, true);
  return fmaxf(v, __int_as_float(m));
}

// ---------------- FPS kernel: one block per batch ----------------
// Exact replica of _fps_order: d = (dx*dx+dy*dy)+dz*dz (no FMA), mind=min,
// argmax with lowest-index-first tie break (contiguous layout makes
// lane order == index order, so ballot+ffs gives the lowest index).
__global__ __launch_bounds__(FT) void fps_kernel(const float* __restrict__ x,
                                                 int* __restrict__ idxs) {
  const int b = blockIdx.x;
  const int t = threadIdx.x;
  const int w = t >> 6;
  const int lane = t & 63;
  const float* xb = x + (size_t)b * NN * 3;

  __shared__ float4 lxyz[NN];   // 64 KB coord mirror (w unused) for broadcast
  __shared__ u64 rkey[2][4];    // per-wave candidate keys, double-buffered

  float px[PT], py[PT], pz[PT], mind[PT];

  // load 16 contiguous points = 12 float4 per thread (fully coalesced block)
  const float4* xb4 = (const float4*)xb;
  float4 f[12];
#pragma unroll
  for (int j = 0; j < 12; ++j) f[j] = xb4[t * 12 + j];
#pragma unroll
  for (int g = 0; g < 4; ++g) {
    float4 a = f[g * 3 + 0], c = f[g * 3 + 1], d = f[g * 3 + 2];
    px[g * 4 + 0] = a.x; py[g * 4 + 0] = a.y; pz[g * 4 + 0] = a.z;
    px[g * 4 + 1] = a.w; py[g * 4 + 1] = c.x; pz[g * 4 + 1] = c.y;
    px[g * 4 + 2] = c.z; py[g * 4 + 2] = c.w; pz[g * 4 + 2] = d.x;
    px[g * 4 + 3] = d.y; py[g * 4 + 3] = d.z; pz[g * 4 + 3] = d.w;
  }
#pragma unroll
  for (int q = 0; q < PT; ++q) {
    lxyz[t * PT + q] = make_float4(px[q], py[q], pz[q], 0.0f);
    mind[q] = __builtin_inff();
  }
  if (t == 0) idxs[(size_t)b * NN] = 0;
  __syncthreads();

  float4 lp = lxyz[0];
  for (int it = 0; it < NN - 1; ++it) {
    float bestv = -1.0f;
    int bq = 0;
#pragma unroll
    for (int q = 0; q < PT; ++q) {
      float dx = __fsub_rn(px[q], lp.x);
      float dy = __fsub_rn(py[q], lp.y);
      float dz = __fsub_rn(pz[q], lp.z);
      float dd = __fadd_rn(__fadd_rn(__fmul_rn(dx, dx), __fmul_rn(dy, dy)),
                           __fmul_rn(dz, dz));
      float m = fminf(mind[q], dd);
      mind[q] = m;
      if (m > bestv) { bestv = m; bq = q; }   // strict > : earliest q on ties
    }
    int besti = t * PT + bq;

    // wave64 max via DPP (all VALU): result in lane 63
    float r = bestv;
    r = maxdpp<0x111>(r);   // row_shr:1
    r = maxdpp<0x112>(r);   // row_shr:2
    r = maxdpp<0x114>(r);   // row_shr:4
    r = maxdpp<0x118>(r);   // row_shr:8
    r = maxdpp<0x142>(r);   // row_bcast:15
    r = maxdpp<0x143>(r);   // row_bcast:31
    int wmaxb = __builtin_amdgcn_readlane(__float_as_int(r), 63);

    // lowest lane holding the max == lowest candidate index (contiguous layout)
    u64 msk = __ballot(__float_as_int(bestv) == wmaxb);
    int flane = __ffsll(msk) - 1;
    int widx = __builtin_amdgcn_readlane(besti, flane);

    u64 key = ((u64)(u32)wmaxb << 32) | (u32)(0xFFFFFFFFu - (u32)widx);
    if (lane == 0) rkey[it & 1][w] = key;
    __syncthreads();

    u64 k0 = rkey[it & 1][0], k1 = rkey[it & 1][1];
    u64 k2 = rkey[it & 1][2], k3 = rkey[it & 1][3];
    u64 m01 = k0 > k1 ? k0 : k1;
    u64 m23 = k2 > k3 ? k2 : k3;
    u64 km = m01 > m23 ? m01 : m23;
    int last = (int)(0xFFFFFFFFu - (u32)(km & 0xFFFFFFFFu));
    if (t == 0) idxs[(size_t)b * NN + it + 1] = last;
    lp = lxyz[last];
  }
}

// ------------- selection kernel: one block per batch -------------
__global__ __launch_bounds__(SEL_T) void select_kernel(const float* __restrict__ x,
                                                       const float* __restrict__ curv,
                                                       const int* __restrict__ idxs,
                                                       float* __restrict__ out) {
  const int b = blockIdx.x;
  const int t = threadIdx.x;
  __shared__ u64 ka[SS];     // sca keys: (~vbits, i)  -> ascending == desc by v
  __shared__ u64 kb[4096];   // scb keys: (vbits, i)   -> ascending, 1024 pads
  __shared__ float rmn[8], rmx[8];

  const float* cb = curv + (size_t)b * NN;
  const int* ib = idxs + (size_t)b * NN;

  float mn = __builtin_inff(), mx = -__builtin_inff();
  float cv[8];
#pragma unroll
  for (int q = 0; q < 8; ++q) {
    float v = cb[q * SEL_T + t];
    cv[q] = v;
    mn = fminf(mn, v);
    mx = fmaxf(mx, v);
  }
#pragma unroll
  for (int s = 1; s < 64; s <<= 1) {
    mn = fminf(mn, __shfl_xor(mn, s, 64));
    mx = fmaxf(mx, __shfl_xor(mx, s, 64));
  }
  if ((t & 63) == 0) { rmn[t >> 6] = mn; rmx[t >> 6] = mx; }
  __syncthreads();
  mn = rmn[0]; mx = rmx[0];
#pragma unroll
  for (int w = 1; w < 8; ++w) { mn = fminf(mn, rmn[w]); mx = fmaxf(mx, rmx[w]); }
  float denom = __fsub_rn(mx, mn);

#pragma unroll
  for (int q = 0; q < 8; ++q) {
    int i = q * SEL_T + t;
    float cn = __fdiv_rn(__fsub_rn(cv[q], mn), denom);
    int id = ib[i];
    // jnp.linspace(1,0,4096)[id] = 1 - id/4095 (true division; id=4095 -> 0)
    float sv = __fsub_rn(1.0f, __fdiv_rn((float)id, 4095.0f));
    float scv = __fmul_rn(sv, cn);   // sc >= 0 -> bits are order-monotone
    u32 vb = __float_as_uint(scv);
    if (i < SS)
      ka[i] = ((u64)(vb ^ 0xFFFFFFFFu) << 32) | (u32)i;
    else
      kb[i - SS] = ((u64)vb << 32) | (u32)(i - SS);
  }
  for (int i = NBB + t; i < 4096; i += SEL_T) kb[i] = ~0ULL;  // pads to the top
  __syncthreads();

  // bitonic sort ka ascending (n=1024, 512 pairs: one per thread)
  for (u32 k = 2; k <= SS; k <<= 1) {
    for (u32 j = k >> 1; j > 0; j >>= 1) {
      u32 p = (u32)t;
      u32 i = ((p & ~(j - 1)) << 1) | (p & (j - 1));
      u32 l = i | j;
      bool up = ((i & k) == 0);
      u64 a = ka[i], c = ka[l];
      if ((a > c) == up) { ka[i] = c; ka[l] = a; }
      __syncthreads();
    }
  }
  // bitonic sort kb ascending (n=4096, 2048 pairs: 4 per thread)
  for (u32 k = 2; k <= 4096; k <<= 1) {
    for (u32 j = k >> 1; j > 0; j >>= 1) {
#pragma unroll
      for (u32 p = (u32)t; p < 2048; p += SEL_T) {
        u32 i = ((p & ~(j - 1)) << 1) | (p & (j - 1));
        u32 l = i | j;
        bool up = ((i & k) == 0);
        u64 a = kb[i], c = kb[l];
        if ((a > c) == up) { kb[i] = c; kb[l] = a; }
      }
      __syncthreads();
    }
  }

  // final[j]: j<922 -> ba_idx[j]; else tb beats ba ? tb_idx[j] : ba_idx[j]
#pragma unroll
  for (int j0 = 0; j0 < SS; j0 += SEL_T) {
    int j = j0 + t;
    u64 A = ka[j];
    int baid = (int)(u32)(A & 0xFFFFFFFFu);
    u32 babits = ((u32)(A >> 32)) ^ 0xFFFFFFFFu;
    int fin = baid;
    if (j >= SS - EE) {
      u64 Bk = kb[2048 + j];           // largest-1024 of scb, ascending
      u32 tbbits = (u32)(Bk >> 32);
      if (tbbits > babits) fin = (int)(u32)(Bk & 0xFFFFFFFFu) + SS;
    }
    int pt = ib[fin];
    out[(size_t)b * SS + j] = (float)fin;
    const float* xp = x + ((size_t)b * NN + (size_t)pt) * 3;
    float* op = out + (size_t)BB * SS + ((size_t)b * SS + (size_t)j) * 3;
    op[0] = xp[0];
    op[1] = xp[1];
    op[2] = xp[2];
  }
}

extern "C" void kernel_launch(void* const* d_in, const int* in_sizes, int n_in,
                              void* d_out, int out_size, void* d_ws, size_t ws_size,
                              hipStream_t stream) {
  (void)in_sizes; (void)n_in; (void)out_size; (void)ws_size;
  const float* x = (const float*)d_in[0];
  const float* curv = (const float*)d_in[1];
  int* idxs = (int*)d_ws;             // B*N int32 = 128 KB scratch
  float* out = (float*)d_out;

  fps_kernel<<<BB, FT, 0, stream>>>(x, idxs);
  select_kernel<<<BB, SEL_T, 0, stream>>>(x, curv, idxs, out);
}